// Round 6
// baseline (15078.941 us; speedup 1.0000x reference)
//
#include <hip/hip_runtime.h>
#include <stdint.h>

typedef unsigned short ushort_t;
typedef unsigned int uint32;

#define SEQ   2048
#define BATCH 64
#define INDIM 128
#define HID   256
#define NGRP  4         // independent batch groups (16 rows each)
#define NWGG  16        // WGs per group (16 hidden cols each)
#define HSZ   (BATCH*SEQ*HID)

typedef __attribute__((ext_vector_type(8))) short short8;
typedef __attribute__((ext_vector_type(4))) float float4_t;
typedef __attribute__((ext_vector_type(4))) uint32 uint4_t;

__device__ __forceinline__ ushort_t f2bf(float f) {
  uint32 u = __builtin_bit_cast(uint32, f);
  u += 0x7FFFu + ((u >> 16) & 1u);           // round-to-nearest-even
  return (ushort_t)(u >> 16);
}
__device__ __forceinline__ float fast_sigmoid(float x) {
  return 1.0f / (1.0f + __expf(-x));
}
__device__ __forceinline__ float fast_tanh(float x) {
  return 1.0f - 2.0f / (__expf(2.0f * x) + 1.0f);
}
template<int CTRL>
__device__ __forceinline__ float bcast_quad(float v) {
  int r = __builtin_amdgcn_mov_dpp(__builtin_bit_cast(int, v), CTRL, 0xF, 0xF, true);
  return __builtin_bit_cast(float, r);
}

// ---- bypass (sc0 sc1) ops: coherent via MALL (round-0/4 proven forms) ----
__device__ __forceinline__ void load16_bypass(uint4_t& d, const uint32* p) {
  asm volatile("global_load_dwordx4 %0, %1, off sc0 sc1"
               : "=v"(d) : "v"(p) : "memory");
}
__device__ __forceinline__ void store_dword_bypass(uint32* p, uint32 v) {
  asm volatile("global_store_dword %0, %1, off sc0 sc1"
               :: "v"(p), "v"(v) : "memory");
}
__device__ __forceinline__ void issue_poll(uint32& v, const uint32* p) {
  asm volatile("global_load_dword %0, %1, off sc0 sc1"
               : "=v"(v) : "v"(p) : "memory");
}
__device__ __forceinline__ void wait_vm1(uint32& v) {
  asm volatile("s_waitcnt vmcnt(1)" : "+v"(v) :: "memory");
}
__device__ __forceinline__ void drain_tied2(uint32& a, uint32& b) {
  asm volatile("s_waitcnt vmcnt(0)" : "+v"(a), "+v"(b) :: "memory");
}
// ---- plain cached loads via asm (keeps the compiler out of vmcnt) ----
__device__ __forceinline__ void load16_plain(short8& d, const ushort_t* p) {
  asm volatile("global_load_dwordx4 %0, %1, off"
               : "=v"(d) : "v"(p) : "memory");
}
// counted wait: releases exactly the 4 x-prefetch loads (see schedule proof)
__device__ __forceinline__ void wait_xq18(short8* x) {
  asm volatile("s_waitcnt vmcnt(18)"
               : "+v"(x[0]), "+v"(x[1]), "+v"(x[2]), "+v"(x[3]) :: "memory");
}
__device__ __forceinline__ void wait_xq0(short8* x) {
  asm volatile("s_waitcnt vmcnt(0)"
               : "+v"(x[0]), "+v"(x[1]), "+v"(x[2]), "+v"(x[3]) :: "memory");
}
__device__ __forceinline__ void wait16u(uint4_t* h) {
  asm volatile("s_waitcnt vmcnt(0)"
               : "+v"(h[0]),  "+v"(h[1]),  "+v"(h[2]),  "+v"(h[3]),
                 "+v"(h[4]),  "+v"(h[5]),  "+v"(h[6]),  "+v"(h[7]),
                 "+v"(h[8]),  "+v"(h[9]),  "+v"(h[10]), "+v"(h[11]),
                 "+v"(h[12]), "+v"(h[13]), "+v"(h[14]), "+v"(h[15])
               :: "memory");
}

// ---------------------------------------------------------------------------
// Pack kernel (BM2/bp2/xbf identical to validated packing).
// hpub: one dword per (row, hidden col) = {bf16 h, tag16}.
//   dword idx (within grp,buf) = row*256 + col;  4 grp x 2 buf x 4096 dwords.
// Producer (step t): each lane stores ONE dword {data, t+1} -- naturally
// aligned dword stores are single-copy atomic, so data+tag travel together.
// Consumer lane (lhi,llo): row llo, dwords f*32+lhi*8+0..7 per fragment f.
// Tags monotone per dword (t, t+2, ...). All tags zeroed here.
// ---------------------------------------------------------------------------
__global__ void pack_init(const float* __restrict__ x,
                          const float* __restrict__ Wf, const float* __restrict__ Wi,
                          const float* __restrict__ Wo, const float* __restrict__ Wc,
                          const float* __restrict__ Uf, const float* __restrict__ Ui,
                          const float* __restrict__ Uo, const float* __restrict__ Uc,
                          const float* __restrict__ bf_, const float* __restrict__ bi_,
                          const float* __restrict__ bo_, const float* __restrict__ bc_,
                          ushort_t* __restrict__ BM2, float* __restrict__ bp2,
                          ushort_t* __restrict__ xbf, uint32* __restrict__ hpubz) {
  int idx = blockIdx.x * 256 + threadIdx.x;   // exactly SEQ*BATCH*INDIM threads
  {
    int e = idx & 7, lane = (idx >> 3) & 63, q = (idx >> 9) & 3,
        grp = (idx >> 11) & 3, t = idx >> 13;
    if (t < SEQ) {
      int row = grp * 16 + (lane & 15);
      int k = q * 32 + (lane >> 4) * 8 + e;
      xbf[idx] = f2bf(x[(row * SEQ + t) * INDIM + k]);
    }
  }
  if (idx < 64 * 12 * 512) {                  // B fragments
    int e = idx & 7, lane = (idx >> 3) & 63;
    int kf = (idx >> 9) % 12, jw = (idx >> 9) / 12;
    int w = jw & 3, j = jw >> 2;
    int llo = lane & 15, lhi = lane >> 4;
    int n = j * 16 + w * 4 + (llo >> 2);
    int g = llo & 3;
    int k = kf * 32 + lhi * 8 + e;
    const float* W4[4] = {Wf, Wi, Wo, Wc};
    const float* U4[4] = {Uf, Ui, Uo, Uc};
    float v = (k < HID) ? W4[g][k * HID + n] : U4[g][(k - HID) * HID + n];
    BM2[idx] = f2bf(v);
  }
  if (idx < 1024) {                           // packed bias
    int llo = idx & 15, jw = idx >> 4;
    int w = jw & 3, j = jw >> 2;
    int n = j * 16 + w * 4 + (llo >> 2);
    int g = llo & 3;
    const float* B4[4] = {bf_, bi_, bo_, bc_};
    bp2[idx] = B4[g][n];
  }
  if (idx < NGRP * 2 * 4096) hpubz[idx] = 0;  // zero hpub incl. all tags
}

// ---------------------------------------------------------------------------
// Persistent recurrence, barrier-free, TAGGED-DWORD exchange with
// speculative fetch + cheap narrow-probe fallback.
// Steady-state VMEM schedule per iteration (ALL loop VMEM via asm; exact):
//   [inherited: xpf x4, publish, out = 6]
//   A: wide x16 (speculative tagged fetch)          -> 22 outstanding
//   wait vmcnt(18): releases oldest 4 = xpf -> xq ready; x-MFMA overlaps A
//   wait vmcnt(0) tied to hd: wide complete -> validate 64 embedded tags
//     hit  : proceed (sync cost = one fetch RT, no drain/flag anywhere)
//     miss : narrow probe (1 dword/lane, tag>=t, R4's double-poll; 256B/wave
//            per retry -- NO traffic storm) then ONE wide re-fetch+validate
//   xpf x4 (t+1) -> h-MFMA (dual-acc) -> gates -> publish dword -> out dword
// Overwrite induction unchanged: buffer holding tag t receives t+2 only
// after every wave's tag-t read completed (publish follows poll+use in
// program/data order) -> equality validate is exact, probes are monotone.
// ---------------------------------------------------------------------------
__global__ __launch_bounds__(256, 1) void lstm_seq(
    const ushort_t* __restrict__ xbf, const ushort_t* __restrict__ BM2,
    const float* __restrict__ bp2, uint32* hpub, float* __restrict__ out)
{
  const int i    = blockIdx.x & 3;
  const int j    = blockIdx.x >> 2;
  const int tid  = threadIdx.x;
  const int wave = tid >> 6;
  const int lane = tid & 63;
  const int lhi  = lane >> 4;
  const int llo  = lane & 15;
  const int Lr   = lane & 3;           // gate row within the quad this lane owns
  const int csub = llo >> 2;           // hidden col within the slice
  const int row  = lhi * 4 + Lr;       // batch row (0..15) this lane publishes

  // persistent B fragments (48 VGPRs, all 2048 steps)
  short8 bfrag[12];
  {
    const ushort_t* bsrc = BM2 + (size_t)((j * 4 + wave) * 12) * 512 + lane * 8;
#pragma unroll
    for (int kf = 0; kf < 12; ++kf)
      bfrag[kf] = *(const short8*)(bsrc + kf * 512);
  }
  const float bias = bp2[(j * 4 + wave) * 16 + llo];

  float c_reg[4] = {0.f, 0.f, 0.f, 0.f};
  const int sown = j * 4 + wave;                    // owned slice
  const int colg = sown * 4 + csub;                 // global hidden col

  // x fragments for t=0 (asm loads + tied full drain: clean vmcnt slate)
  short8 xq[4];
  {
    const ushort_t* xs = xbf + (size_t)i * 2048 + lane * 8;
#pragma unroll
    for (int q = 0; q < 4; ++q) load16_plain(xq[q], xs + q * 512);
    wait_xq0(xq);
  }

  for (int t = 0; t < SEQ; ++t) {
    uint4_t hd[16];
    const uint32* cb = hpub + (size_t)(i * 2 + ((t - 1) & 1)) * 4096 + llo * 256;
    if (t > 0) {
      // A: speculative tagged wide fetch (16 x 16B)
#pragma unroll
      for (int f = 0; f < 8; ++f) {
        load16_bypass(hd[2 * f],     cb + f * 32 + lhi * 8);
        load16_bypass(hd[2 * f + 1], cb + f * 32 + lhi * 8 + 4);
      }
      wait_xq18(xq);         // exact: oldest 4 (xpf) done -> xq ready
    }

    // --- x part: overlaps the wide fetch in flight ---
    float4_t acc = {bias, bias, bias, bias};
#pragma unroll
    for (int q = 0; q < 4; ++q)
      acc = __builtin_amdgcn_mfma_f32_16x16x32_bf16(xq[q], bfrag[8 + q], acc, 0, 0, 0);
    float4_t accA = {0.f, 0.f, 0.f, 0.f};
    float4_t accB = {0.f, 0.f, 0.f, 0.f};

    if (t > 0) {
      wait16u(hd);           // wide complete (drains old pub/out acks too)
      const uint32 pat = (uint32)t << 16;
      uint32 bad = 0;
#pragma unroll
      for (int n = 0; n < 16; ++n)
#pragma unroll
        for (int c = 0; c < 4; ++c)
          bad |= (hd[n][c] ^ pat) & 0xFFFF0000u;
      if (!__all((int)(bad == 0u))) {
        // --- narrow probe: 1 dword/lane, slice `lane`, monotone tag >= t ---
        const uint32* pb = hpub + (size_t)(i * 2 + ((t - 1) & 1)) * 4096 +
                           ((lane & 15) << 8) + (lane << 2);
        uint32 va, vb;
        issue_poll(va, pb);
        issue_poll(vb, pb);
        for (;;) {
          wait_vm1(va);
          if (__all((int)((va >> 16) >= (uint32)t))) break;
          issue_poll(va, pb);
          wait_vm1(vb);
          if (__all((int)((vb >> 16) >= (uint32)t))) break;
          issue_poll(vb, pb);
        }
        drain_tied2(va, vb);
        // --- wide re-fetch + validate (rarely loops; backoff if it does) ---
        for (;;) {
#pragma unroll
          for (int f = 0; f < 8; ++f) {
            load16_bypass(hd[2 * f],     cb + f * 32 + lhi * 8);
            load16_bypass(hd[2 * f + 1], cb + f * 32 + lhi * 8 + 4);
          }
          wait16u(hd);
          uint32 bad2 = 0;
#pragma unroll
          for (int n = 0; n < 16; ++n)
#pragma unroll
            for (int c = 0; c < 4; ++c)
              bad2 |= (hd[n][c] ^ pat) & 0xFFFF0000u;
          if (__all((int)(bad2 == 0u))) break;
          __builtin_amdgcn_s_sleep(1);
        }
      }
      // xpf EARLY (oldest of next iteration's inherited ops)
      if (t < SEQ - 1) {
        const ushort_t* xs = xbf + (size_t)((t + 1) * 4 + i) * 2048 + lane * 8;
#pragma unroll
        for (int q = 0; q < 4; ++q) load16_plain(xq[q], xs + q * 512);
      }
      // pack bf16 pairs, dual-accumulator h-MFMA chains
#pragma unroll
      for (int kf = 0; kf < 4; ++kf) {
        uint4_t wA, wB;
        wA[0] = (hd[4 * kf][0]     & 0xFFFFu) | (hd[4 * kf][1]     << 16);
        wA[1] = (hd[4 * kf][2]     & 0xFFFFu) | (hd[4 * kf][3]     << 16);
        wA[2] = (hd[4 * kf + 1][0] & 0xFFFFu) | (hd[4 * kf + 1][1] << 16);
        wA[3] = (hd[4 * kf + 1][2] & 0xFFFFu) | (hd[4 * kf + 1][3] << 16);
        wB[0] = (hd[4 * kf + 2][0] & 0xFFFFu) | (hd[4 * kf + 2][1] << 16);
        wB[1] = (hd[4 * kf + 2][2] & 0xFFFFu) | (hd[4 * kf + 2][3] << 16);
        wB[2] = (hd[4 * kf + 3][0] & 0xFFFFu) | (hd[4 * kf + 3][1] << 16);
        wB[3] = (hd[4 * kf + 3][2] & 0xFFFFu) | (hd[4 * kf + 3][3] << 16);
        accA = __builtin_amdgcn_mfma_f32_16x16x32_bf16(
                   __builtin_bit_cast(short8, wA), bfrag[2 * kf],     accA, 0, 0, 0);
        accB = __builtin_amdgcn_mfma_f32_16x16x32_bf16(
                   __builtin_bit_cast(short8, wB), bfrag[2 * kf + 1], accB, 0, 0, 0);
      }
    } else {
      // t==0: x prefetch for t=1 (keeps inherited-op count at exactly 6)
      const ushort_t* xs = xbf + (size_t)(1 * 4 + i) * 2048 + lane * 8;
#pragma unroll
      for (int q = 0; q < 4; ++q) load16_plain(xq[q], xs + q * 512);
    }

    // --- gates (all four sigmoid, per ref) + cell update ---
    float hv0, hv1, hv2, hv3;
#pragma unroll
    for (int r = 0; r < 4; ++r) {
      float s  = fast_sigmoid(acc[r] + accA[r] + accB[r]);
      float fv = bcast_quad<0x00>(s);
      float iv = bcast_quad<0x55>(s);
      float ov = bcast_quad<0xAA>(s);
      float cv = bcast_quad<0xFF>(s);
      float cn = fv * c_reg[r] + iv * cv;
      c_reg[r] = cn;
      float h  = ov * fast_tanh(cn);
      if      (r == 0) hv0 = h;
      else if (r == 1) hv1 = h;
      else if (r == 2) hv2 = h;
      else             hv3 = h;
    }
    // lane's published value: h[row][colg] (quad-replicated; pick r = Lr)
    float val = (Lr == 0) ? hv0 : (Lr == 1) ? hv1 : (Lr == 2) ? hv2 : hv3;

    if (t < SEQ - 1) {
      // publish h_t: ONE dword {bf16 data, tag t+1}, fire-and-forget
      uint32 pv = (uint32)f2bf(val) | (((uint32)(t + 1)) << 16);
      store_dword_bypass(hpub + (size_t)(i * 2 + (t & 1)) * 4096 +
                         row * 256 + colg, pv);
      // out store (plain, pinned after publish by the asm memory clobber)
      out[((size_t)(16 * i + row) * SEQ + t) * HID + colg] = val;
    } else {
      // final step: hidden_seq row + h_T + c_T (scatter, one value per lane)
      out[((size_t)(16 * i + row) * SEQ + t) * HID + colg] = val;
      out[HSZ + (size_t)(16 * i + row) * HID + colg] = val;
      float cva = (Lr == 0) ? c_reg[0] : (Lr == 1) ? c_reg[1]
                : (Lr == 2) ? c_reg[2] : c_reg[3];
      out[HSZ + BATCH * HID + (size_t)(16 * i + row) * HID + colg] = cva;
    }
  }
}

// ---------------------------------------------------------------------------
// Workspace layout (bytes):
//   [0, 786432)          BM2   bf16 wave-linear B fragments
//   [786432, 790528)     bp2   fp32 1024
//   [790528, 921600)     hpub  4 grp x 2 buf x 4096 dwords = 128KB
//   [1048576, 34603008)  xbf   bf16 fragment-linear x (33.5 MB)
// ---------------------------------------------------------------------------
extern "C" void kernel_launch(void* const* d_in, const int* in_sizes, int n_in,
                              void* d_out, int out_size, void* d_ws, size_t ws_size,
                              hipStream_t stream) {
  const float* xp  = (const float*)d_in[0];
  const float* Uf  = (const float*)d_in[1];
  const float* Wf  = (const float*)d_in[2];
  const float* bf_ = (const float*)d_in[3];
  const float* Ui  = (const float*)d_in[4];
  const float* Wi  = (const float*)d_in[5];
  const float* bi_ = (const float*)d_in[6];
  const float* Uo  = (const float*)d_in[7];
  const float* Wo  = (const float*)d_in[8];
  const float* bo_ = (const float*)d_in[9];
  const float* Uc  = (const float*)d_in[10];
  const float* Wc  = (const float*)d_in[11];
  const float* bc_ = (const float*)d_in[12];

  char* ws = (char*)d_ws;
  ushort_t* BM2   = (ushort_t*)(ws);
  float*    bp2   = (float*)(ws + 786432);
  uint32*   hpub  = (uint32*)(ws + 790528);
  ushort_t* xbf   = (ushort_t*)(ws + 1048576);
  float*    out   = (float*)d_out;

  pack_init<<<65536, 256, 0, stream>>>(xp, Wf, Wi, Wo, Wc, Uf, Ui, Uo, Uc,
                                       bf_, bi_, bo_, bc_, BM2, bp2, xbf, hpub);
  lstm_seq<<<NGRP * NWGG, 256, 0, stream>>>(xbf, BM2, bp2, hpub, out);
}